// Round 3
// baseline (810.118 us; speedup 1.0000x reference)
//
#include <hip/hip_runtime.h>
#include <math.h>

// CriterionLSCos: MSE between 8-neighbor cosine-similarity maps of two
// [16,19,256,256] fp32 tensors.
//
// R2 changes vs R1 (64.5us; all pipes <31% => latency/convoy-bound):
//  - undirected-pair algebra: dot(c,n)==dot(n,c), so each of the 4 forward
//    pairs (E,S,SE,SW) is computed once with weight 2 (1 if partner is a
//    border pixel). Halves dot FMAs and removes the upper tile row
//    (9-row tile, -10% fetch, 4 LDS b64 reads/tensor instead of 6).
//  - leftover backward pairs (partner non-interior: y==1 row, x==1/254
//    cols; 1522/batch) handled by 32 extra border blocks (blockIdx.y==32)
//    that run concurrently with the main grid.
//  - 2-deep register prefetch: loads for ch+2 issued while computing ch
//    (load-to-use distance ~2 iterations >> 900cy HBM latency).
//  - __launch_bounds__(512,8) pins VGPR<=64 for 8 waves/SIMD.

constexpr int BATCH = 16, CH = 19, H = 256, W = 256;
constexpr int BXT = 64, BYT = 8, NT = BXT * BYT;  // 512 threads
constexpr int CX = 128, CY = 8;                   // centers per main block
constexpr int TW2 = 66;                           // float2 slots per tile row
constexpr int TH = 9;                             // tile rows y0..y0+8
constexpr int NP = TW2 * TH;                      // 594 slots
constexpr int NBY = 32;                           // main y-blocks; by==NBY -> border
constexpr int NBORDER = 1522;                     // backward border pairs per batch

__global__ __launch_bounds__(NT, 8)
void cosmap_mse_kernel(const float* __restrict__ preds,
                       const float* __restrict__ soft,
                       double* __restrict__ acc_out) {
  __shared__ float2 sp[2][NP];
  __shared__ float2 ss[2][NP];
  __shared__ float wsum[NT / 64];

  const int tx = threadIdx.x, ty = threadIdx.y;
  const int tid = ty * BXT + tx;
  const size_t base = (size_t)blockIdx.z * CH * H * W;

  float local = 0.f;

  if (blockIdx.y == NBY) {
    // ---------- border blocks: backward pairs whose partner is non-interior
    const float* P = preds + base;
    const float* S = soft + base;
    for (int t = blockIdx.x * NT + tid; t < NBORDER; t += 2 * NT) {
      int cy, cx, ny, nx;
      if (t < 762) {            // centers (1,x): N / NW / NE vs row 0
        int d = t / 254, k = t - d * 254;
        cy = 1; cx = 1 + k; ny = 0;
        nx = cx + (d == 0 ? 0 : (d == 1 ? -1 : 1));
      } else if (t < 1016) {    // centers (y,1): W vs col 0
        int k = t - 762; cy = 1 + k; cx = 1; ny = cy; nx = 0;
      } else if (t < 1269) {    // centers (y,1), y>=2: NW vs col 0
        int k = t - 1016; cy = 2 + k; cx = 1; ny = cy - 1; nx = 0;
      } else {                  // centers (y,254), y>=2: NE vs col 255
        int k = t - 1269; cy = 2 + k; cx = 254; ny = cy - 1; nx = 255;
      }
      const int ec = cy * W + cx, en = ny * W + nx;
      float dp = 0.f, n1 = 0.f, n2 = 0.f, dq = 0.f, m1 = 0.f, m2 = 0.f;
      for (int c = 0; c < CH; ++c) {
        const int o = c * (H * W);
        float pc = P[o + ec], pn = P[o + en];
        float sc = S[o + ec], sn = S[o + en];
        dp = fmaf(pc, pn, dp); n1 = fmaf(pc, pc, n1); n2 = fmaf(pn, pn, n2);
        dq = fmaf(sc, sn, dq); m1 = fmaf(sc, sc, m1); m2 = fmaf(sn, sn, m2);
      }
      float mp = dp * (1.0f / sqrtf(n1)) * (1.0f / sqrtf(n2));
      float ms = dq * (1.0f / sqrtf(m1)) * (1.0f / sqrtf(m2));
      float d = mp - ms;
      local = fmaf(d, d, local);  // weight 1
    }
  } else {
    // ---------- main blocks: forward pairs E,S,SE,SW with weight 1+interior
    const int x0 = 1 + blockIdx.x * CX;
    const int y0 = 1 + blockIdx.y * CY;

    const int p0 = tid;
    const bool has2 = tid < (NP - NT);  // 82 threads own a second slot
    const int p1 = has2 ? tid + NT : tid;

    bool ov0, ov1; int f0, f1;
    {
      int j = p0 / TW2, i2 = p0 - j * TW2;
      int gy = y0 + j; gy = gy > H - 1 ? H - 1 : gy;   // tile row j = pixel y0+j
      int gs = x0 - 1 + 2 * i2;
      ov0 = gs >= W - 1;
      f0 = (gy * W + (ov0 ? W - 2 : gs)) >> 1;
    }
    {
      int j = p1 / TW2, i2 = p1 - j * TW2;
      int gy = y0 + j; gy = gy > H - 1 ? H - 1 : gy;
      int gs = x0 - 1 + 2 * i2;
      ov1 = gs >= W - 1;
      f1 = (gy * W + (ov1 ? W - 2 : gs)) >> 1;
    }

    const float2* pp = (const float2*)(preds + base);
    const float2* qq = (const float2*)(soft + base);
    constexpr int CS2 = H * W / 2;

    // 2-deep prefetch: A = ch, B = ch+1 in flight
    float2 Ap0 = pp[f0], Aq0 = qq[f0], Ap1 = pp[f1], Aq1 = qq[f1];
    float2 Bp0 = pp[f0 + CS2], Bq0 = qq[f0 + CS2];
    float2 Bp1 = pp[f1 + CS2], Bq1 = qq[f1 + CS2];

    // forward dot accumulators: [E,S,SE,SW] x {c0,c1} x {preds,soft}
    float dE0 = 0, dS0 = 0, dSE0 = 0, dSW0 = 0;
    float dE1 = 0, dS1 = 0, dSE1 = 0, dSW1 = 0;
    float eE0 = 0, eS0 = 0, eSE0 = 0, eSW0 = 0;
    float eE1 = 0, eS1 = 0, eSE1 = 0, eSW1 = 0;
    float2 np0 = {0, 0}, np1 = {0, 0}, nq0 = {0, 0}, nq1 = {0, 0};

    const int r0 = ty * TW2 + tx;  // center row = tile row ty; lower = ty+1

#pragma unroll 2
    for (int ch = 0; ch < CH; ++ch) {
      float2* SP = sp[ch & 1];
      float2* SS = ss[ch & 1];
      float2 wp0 = Ap0; if (ov0) wp0.x = wp0.y;
      float2 wq0 = Aq0; if (ov0) wq0.x = wq0.y;
      float2 wp1 = Ap1; if (ov1) wp1.x = wp1.y;
      float2 wq1 = Aq1; if (ov1) wq1.x = wq1.y;
      SP[p0] = wp0; SS[p0] = wq0;
      if (has2) { SP[p1] = wp1; SS[p1] = wq1; }
      np0.x = fmaf(wp0.x, wp0.x, np0.x); np0.y = fmaf(wp0.y, wp0.y, np0.y);
      nq0.x = fmaf(wq0.x, wq0.x, nq0.x); nq0.y = fmaf(wq0.y, wq0.y, nq0.y);
      if (has2) {
        np1.x = fmaf(wp1.x, wp1.x, np1.x); np1.y = fmaf(wp1.y, wp1.y, np1.y);
        nq1.x = fmaf(wq1.x, wq1.x, nq1.x); nq1.y = fmaf(wq1.y, wq1.y, nq1.y);
      }
      // rotate prefetch regs; issue loads for ch+2
      Ap0 = Bp0; Aq0 = Bq0; Ap1 = Bp1; Aq1 = Bq1;
      if (ch + 2 < CH) {
        const int o = (ch + 2) * CS2;
        Bp0 = pp[f0 + o]; Bq0 = qq[f0 + o];
        Bp1 = pp[f1 + o]; Bq1 = qq[f1 + o];
      }
      __syncthreads();
      {
        float2 m0 = SP[r0], m1 = SP[r0 + 1];
        float2 l0 = SP[r0 + TW2], l1 = SP[r0 + TW2 + 1];
        dE0  = fmaf(m0.y, m1.x, dE0);   dE1  = fmaf(m1.x, m1.y, dE1);
        dS0  = fmaf(m0.y, l0.y, dS0);   dS1  = fmaf(m1.x, l1.x, dS1);
        dSE0 = fmaf(m0.y, l1.x, dSE0);  dSE1 = fmaf(m1.x, l1.y, dSE1);
        dSW0 = fmaf(m0.y, l0.x, dSW0);  dSW1 = fmaf(m1.x, l0.y, dSW1);
      }
      {
        float2 m0 = SS[r0], m1 = SS[r0 + 1];
        float2 l0 = SS[r0 + TW2], l1 = SS[r0 + TW2 + 1];
        eE0  = fmaf(m0.y, m1.x, eE0);   eE1  = fmaf(m1.x, m1.y, eE1);
        eS0  = fmaf(m0.y, l0.y, eS0);   eS1  = fmaf(m1.x, l1.x, eS1);
        eSE0 = fmaf(m0.y, l1.x, eSE0);  eSE1 = fmaf(m1.x, l1.y, eSE1);
        eSW0 = fmaf(m0.y, l0.x, eSW0);  eSW1 = fmaf(m1.x, l0.y, eSW1);
      }
    }

    // inverse norms -> buffer 1 (all waves past barrier(18) => buf1 free)
    {
      float2 r;
      r.x = 1.0f / sqrtf(np0.x); r.y = 1.0f / sqrtf(np0.y); sp[1][p0] = r;
      r.x = 1.0f / sqrtf(nq0.x); r.y = 1.0f / sqrtf(nq0.y); ss[1][p0] = r;
      if (has2) {
        r.x = 1.0f / sqrtf(np1.x); r.y = 1.0f / sqrtf(np1.y); sp[1][p1] = r;
        r.x = 1.0f / sqrtf(nq1.x); r.y = 1.0f / sqrtf(nq1.y); ss[1][p1] = r;
      }
    }
    __syncthreads();

    {
      const float2* RP = sp[1];
      const float2* RS = ss[1];
      float2 rm0 = RP[r0], rm1 = RP[r0 + 1];
      float2 rl0 = RP[r0 + TW2], rl1 = RP[r0 + TW2 + 1];
      float2 tm0 = RS[r0], tm1 = RS[r0 + 1];
      float2 tl0 = RS[r0 + TW2], tl1 = RS[r0 + TW2 + 1];

      const int px0 = x0 + 2 * tx, px1 = px0 + 1, py = y0 + ty;
      const bool vy = py <= H - 2;
      const float wS = (py + 1 <= H - 2) ? 2.f : 1.f;  // same for c0/c1

      if (vy && px0 <= W - 2) {
        const float wE  = (px0 + 1 <= W - 2) ? 2.f : 1.f;
        const float wSE = (px0 + 1 <= W - 2) ? wS : 1.f;
        const float wSW = (px0 - 1 >= 1) ? wS : 1.f;
        float d;
        d = dE0  * rm0.y * rm1.x - eE0  * tm0.y * tm1.x; local = fmaf(wE  * d, d, local);
        d = dS0  * rm0.y * rl0.y - eS0  * tm0.y * tl0.y; local = fmaf(wS  * d, d, local);
        d = dSE0 * rm0.y * rl1.x - eSE0 * tm0.y * tl1.x; local = fmaf(wSE * d, d, local);
        d = dSW0 * rm0.y * rl0.x - eSW0 * tm0.y * tl0.x; local = fmaf(wSW * d, d, local);
      }
      if (vy && px1 <= W - 2) {
        const float wE  = (px1 + 1 <= W - 2) ? 2.f : 1.f;
        const float wSE = (px1 + 1 <= W - 2) ? wS : 1.f;
        const float wSW = (px1 - 1 >= 1) ? wS : 1.f;  // always 2-ish here
        float d;
        d = dE1  * rm1.x * rm1.y - eE1  * tm1.x * tm1.y; local = fmaf(wE  * d, d, local);
        d = dS1  * rm1.x * rl1.x - eS1  * tm1.x * tl1.x; local = fmaf(wS  * d, d, local);
        d = dSE1 * rm1.x * rl1.y - eSE1 * tm1.x * tl1.y; local = fmaf(wSE * d, d, local);
        d = dSW1 * rm1.x * rl0.y - eSW1 * tm1.x * tl0.y; local = fmaf(wSW * d, d, local);
      }
    }
  }

  // ---------- block reduction (both paths)
#pragma unroll
  for (int o = 32; o > 0; o >>= 1) local += __shfl_down(local, o, 64);
  if ((tid & 63) == 0) wsum[tid >> 6] = local;
  __syncthreads();
  if (tid == 0) {
    float s = 0.f;
#pragma unroll
    for (int w = 0; w < NT / 64; ++w) s += wsum[w];
    atomicAdd(acc_out, (double)s);
  }
}

__global__ void finalize_kernel(const double* __restrict__ acc,
                                float* __restrict__ out) {
  constexpr double cnt = (double)BATCH * 8.0 * (H - 2) * (W - 2);
  out[0] = (float)(acc[0] / cnt);
}

extern "C" void kernel_launch(void* const* d_in, const int* in_sizes, int n_in,
                              void* d_out, int out_size, void* d_ws, size_t ws_size,
                              hipStream_t stream) {
  const float* preds = (const float*)d_in[0];
  const float* soft = (const float*)d_in[1];
  double* acc = (double*)d_ws;

  hipMemsetAsync(d_ws, 0, sizeof(double), stream);  // ws is 0xAA-poisoned

  dim3 block(BXT, BYT);
  dim3 grid((W - 2 + CX - 1) / CX, NBY + 1, BATCH);  // y==NBY -> border blocks
  cosmap_mse_kernel<<<grid, block, 0, stream>>>(preds, soft, acc);
  finalize_kernel<<<1, 1, 0, stream>>>(acc, (float*)d_out);
}

// Round 7
// 616.936 us; speedup vs baseline: 1.3131x; 1.3131x over previous
//
#include <hip/hip_runtime.h>
#include <math.h>

// CriterionLSCos: MSE between 8-neighbor cosine-similarity maps of two
// [16,19,256,256] fp32 tensors.
//
// R3 post-mortem: __launch_bounds__(512,8) capped VGPR at 64 -> compiler
// allocated 32 and SPILLED the accumulators (FETCH+WRITE ~2GB of scratch
// traffic, 703us). This kernel = same algorithm with (512,4): VGPR cap 128,
// no spill. (R4/R5/R6 benches were broker timeouts — unchanged resubmit.)
//
// Algorithm (from R2, passed):
//  - undirected-pair algebra: each forward pair (E,S,SE,SW) computed once,
//    weight 2 (1 if partner is border). Halves dot FMAs, 9-row tile.
//  - leftover backward border pairs (1522/batch) in 32 concurrent border
//    blocks (blockIdx.y==NBY).
//  - 2-deep register prefetch across the single per-channel barrier.

constexpr int BATCH = 16, CH = 19, H = 256, W = 256;
constexpr int BXT = 64, BYT = 8, NT = BXT * BYT;  // 512 threads
constexpr int CX = 128, CY = 8;                   // centers per main block
constexpr int TW2 = 66;                           // float2 slots per tile row
constexpr int TH = 9;                             // tile rows y0..y0+8
constexpr int NP = TW2 * TH;                      // 594 slots
constexpr int NBY = 32;                           // main y-blocks; by==NBY -> border
constexpr int NBORDER = 1522;                     // backward border pairs per batch

__global__ __launch_bounds__(NT, 4)   // VGPR cap 128: room for accs, no spill
void cosmap_mse_kernel(const float* __restrict__ preds,
                       const float* __restrict__ soft,
                       double* __restrict__ acc_out) {
  __shared__ float2 sp[2][NP];
  __shared__ float2 ss[2][NP];
  __shared__ float wsum[NT / 64];

  const int tx = threadIdx.x, ty = threadIdx.y;
  const int tid = ty * BXT + tx;
  const size_t base = (size_t)blockIdx.z * CH * H * W;

  float local = 0.f;

  if (blockIdx.y == NBY) {
    // ---------- border blocks: backward pairs whose partner is non-interior
    const float* P = preds + base;
    const float* S = soft + base;
    for (int t = blockIdx.x * NT + tid; t < NBORDER; t += 2 * NT) {
      int cy, cx, ny, nx;
      if (t < 762) {            // centers (1,x): N / NW / NE vs row 0
        int d = t / 254, k = t - d * 254;
        cy = 1; cx = 1 + k; ny = 0;
        nx = cx + (d == 0 ? 0 : (d == 1 ? -1 : 1));
      } else if (t < 1016) {    // centers (y,1): W vs col 0
        int k = t - 762; cy = 1 + k; cx = 1; ny = cy; nx = 0;
      } else if (t < 1269) {    // centers (y,1), y>=2: NW vs col 0
        int k = t - 1016; cy = 2 + k; cx = 1; ny = cy - 1; nx = 0;
      } else {                  // centers (y,254), y>=2: NE vs col 255
        int k = t - 1269; cy = 2 + k; cx = 254; ny = cy - 1; nx = 255;
      }
      const int ec = cy * W + cx, en = ny * W + nx;
      float dp = 0.f, n1 = 0.f, n2 = 0.f, dq = 0.f, m1 = 0.f, m2 = 0.f;
      for (int c = 0; c < CH; ++c) {
        const int o = c * (H * W);
        float pc = P[o + ec], pn = P[o + en];
        float sc = S[o + ec], sn = S[o + en];
        dp = fmaf(pc, pn, dp); n1 = fmaf(pc, pc, n1); n2 = fmaf(pn, pn, n2);
        dq = fmaf(sc, sn, dq); m1 = fmaf(sc, sc, m1); m2 = fmaf(sn, sn, m2);
      }
      float mp = dp * (1.0f / sqrtf(n1)) * (1.0f / sqrtf(n2));
      float ms = dq * (1.0f / sqrtf(m1)) * (1.0f / sqrtf(m2));
      float d = mp - ms;
      local = fmaf(d, d, local);  // weight 1
    }
  } else {
    // ---------- main blocks: forward pairs E,S,SE,SW
    const int x0 = 1 + blockIdx.x * CX;
    const int y0 = 1 + blockIdx.y * CY;

    const int p0 = tid;
    const bool has2 = tid < (NP - NT);  // 82 threads own a second slot
    const int p1 = has2 ? tid + NT : tid;

    bool ov0, ov1; int f0, f1;
    {
      int j = p0 / TW2, i2 = p0 - j * TW2;
      int gy = y0 + j; gy = gy > H - 1 ? H - 1 : gy;
      int gs = x0 - 1 + 2 * i2;
      ov0 = gs >= W - 1;
      f0 = (gy * W + (ov0 ? W - 2 : gs)) >> 1;
    }
    {
      int j = p1 / TW2, i2 = p1 - j * TW2;
      int gy = y0 + j; gy = gy > H - 1 ? H - 1 : gy;
      int gs = x0 - 1 + 2 * i2;
      ov1 = gs >= W - 1;
      f1 = (gy * W + (ov1 ? W - 2 : gs)) >> 1;
    }

    const float2* pp = (const float2*)(preds + base);
    const float2* qq = (const float2*)(soft + base);
    constexpr int CS2 = H * W / 2;

    // 2-deep prefetch: A = ch, B = ch+1 in flight
    float2 Ap0 = pp[f0], Aq0 = qq[f0], Ap1 = pp[f1], Aq1 = qq[f1];
    float2 Bp0 = pp[f0 + CS2], Bq0 = qq[f0 + CS2];
    float2 Bp1 = pp[f1 + CS2], Bq1 = qq[f1 + CS2];

    float dE0 = 0, dS0 = 0, dSE0 = 0, dSW0 = 0;
    float dE1 = 0, dS1 = 0, dSE1 = 0, dSW1 = 0;
    float eE0 = 0, eS0 = 0, eSE0 = 0, eSW0 = 0;
    float eE1 = 0, eS1 = 0, eSE1 = 0, eSW1 = 0;
    float2 np0 = {0, 0}, np1 = {0, 0}, nq0 = {0, 0}, nq1 = {0, 0};

    const int r0 = ty * TW2 + tx;

#pragma unroll 2
    for (int ch = 0; ch < CH; ++ch) {
      float2* SP = sp[ch & 1];
      float2* SS = ss[ch & 1];
      float2 wp0 = Ap0; if (ov0) wp0.x = wp0.y;
      float2 wq0 = Aq0; if (ov0) wq0.x = wq0.y;
      float2 wp1 = Ap1; if (ov1) wp1.x = wp1.y;
      float2 wq1 = Aq1; if (ov1) wq1.x = wq1.y;
      SP[p0] = wp0; SS[p0] = wq0;
      if (has2) { SP[p1] = wp1; SS[p1] = wq1; }
      np0.x = fmaf(wp0.x, wp0.x, np0.x); np0.y = fmaf(wp0.y, wp0.y, np0.y);
      nq0.x = fmaf(wq0.x, wq0.x, nq0.x); nq0.y = fmaf(wq0.y, wq0.y, nq0.y);
      if (has2) {
        np1.x = fmaf(wp1.x, wp1.x, np1.x); np1.y = fmaf(wp1.y, wp1.y, np1.y);
        nq1.x = fmaf(wq1.x, wq1.x, nq1.x); nq1.y = fmaf(wq1.y, wq1.y, nq1.y);
      }
      Ap0 = Bp0; Aq0 = Bq0; Ap1 = Bp1; Aq1 = Bq1;
      if (ch + 2 < CH) {
        const int o = (ch + 2) * CS2;
        Bp0 = pp[f0 + o]; Bq0 = qq[f0 + o];
        Bp1 = pp[f1 + o]; Bq1 = qq[f1 + o];
      }
      __syncthreads();
      {
        float2 m0 = SP[r0], m1 = SP[r0 + 1];
        float2 l0 = SP[r0 + TW2], l1 = SP[r0 + TW2 + 1];
        dE0  = fmaf(m0.y, m1.x, dE0);   dE1  = fmaf(m1.x, m1.y, dE1);
        dS0  = fmaf(m0.y, l0.y, dS0);   dS1  = fmaf(m1.x, l1.x, dS1);
        dSE0 = fmaf(m0.y, l1.x, dSE0);  dSE1 = fmaf(m1.x, l1.y, dSE1);
        dSW0 = fmaf(m0.y, l0.x, dSW0);  dSW1 = fmaf(m1.x, l0.y, dSW1);
      }
      {
        float2 m0 = SS[r0], m1 = SS[r0 + 1];
        float2 l0 = SS[r0 + TW2], l1 = SS[r0 + TW2 + 1];
        eE0  = fmaf(m0.y, m1.x, eE0);   eE1  = fmaf(m1.x, m1.y, eE1);
        eS0  = fmaf(m0.y, l0.y, eS0);   eS1  = fmaf(m1.x, l1.x, eS1);
        eSE0 = fmaf(m0.y, l1.x, eSE0);  eSE1 = fmaf(m1.x, l1.y, eSE1);
        eSW0 = fmaf(m0.y, l0.x, eSW0);  eSW1 = fmaf(m1.x, l0.y, eSW1);
      }
    }

    // inverse norms -> buffer 1
    {
      float2 r;
      r.x = 1.0f / sqrtf(np0.x); r.y = 1.0f / sqrtf(np0.y); sp[1][p0] = r;
      r.x = 1.0f / sqrtf(nq0.x); r.y = 1.0f / sqrtf(nq0.y); ss[1][p0] = r;
      if (has2) {
        r.x = 1.0f / sqrtf(np1.x); r.y = 1.0f / sqrtf(np1.y); sp[1][p1] = r;
        r.x = 1.0f / sqrtf(nq1.x); r.y = 1.0f / sqrtf(nq1.y); ss[1][p1] = r;
      }
    }
    __syncthreads();

    {
      const float2* RP = sp[1];
      const float2* RS = ss[1];
      float2 rm0 = RP[r0], rm1 = RP[r0 + 1];
      float2 rl0 = RP[r0 + TW2], rl1 = RP[r0 + TW2 + 1];
      float2 tm0 = RS[r0], tm1 = RS[r0 + 1];
      float2 tl0 = RS[r0 + TW2], tl1 = RS[r0 + TW2 + 1];

      const int px0 = x0 + 2 * tx, px1 = px0 + 1, py = y0 + ty;
      const bool vy = py <= H - 2;
      const float wS = (py + 1 <= H - 2) ? 2.f : 1.f;

      if (vy && px0 <= W - 2) {
        const float wE  = (px0 + 1 <= W - 2) ? 2.f : 1.f;
        const float wSE = (px0 + 1 <= W - 2) ? wS : 1.f;
        const float wSW = (px0 - 1 >= 1) ? wS : 1.f;
        float d;
        d = dE0  * rm0.y * rm1.x - eE0  * tm0.y * tm1.x; local = fmaf(wE  * d, d, local);
        d = dS0  * rm0.y * rl0.y - eS0  * tm0.y * tl0.y; local = fmaf(wS  * d, d, local);
        d = dSE0 * rm0.y * rl1.x - eSE0 * tm0.y * tl1.x; local = fmaf(wSE * d, d, local);
        d = dSW0 * rm0.y * rl0.x - eSW0 * tm0.y * tl0.x; local = fmaf(wSW * d, d, local);
      }
      if (vy && px1 <= W - 2) {
        const float wE  = (px1 + 1 <= W - 2) ? 2.f : 1.f;
        const float wSE = (px1 + 1 <= W - 2) ? wS : 1.f;
        const float wSW = (px1 - 1 >= 1) ? wS : 1.f;
        float d;
        d = dE1  * rm1.x * rm1.y - eE1  * tm1.x * tm1.y; local = fmaf(wE  * d, d, local);
        d = dS1  * rm1.x * rl1.x - eS1  * tm1.x * tl1.x; local = fmaf(wS  * d, d, local);
        d = dSE1 * rm1.x * rl1.y - eSE1 * tm1.x * tl1.y; local = fmaf(wSE * d, d, local);
        d = dSW1 * rm1.x * rl0.y - eSW1 * tm1.x * tl0.y; local = fmaf(wSW * d, d, local);
      }
    }
  }

  // ---------- block reduction (both paths)
#pragma unroll
  for (int o = 32; o > 0; o >>= 1) local += __shfl_down(local, o, 64);
  if ((tid & 63) == 0) wsum[tid >> 6] = local;
  __syncthreads();
  if (tid == 0) {
    float s = 0.f;
#pragma unroll
    for (int w = 0; w < NT / 64; ++w) s += wsum[w];
    atomicAdd(acc_out, (double)s);
  }
}

__global__ void finalize_kernel(const double* __restrict__ acc,
                                float* __restrict__ out) {
  constexpr double cnt = (double)BATCH * 8.0 * (H - 2) * (W - 2);
  out[0] = (float)(acc[0] / cnt);
}

extern "C" void kernel_launch(void* const* d_in, const int* in_sizes, int n_in,
                              void* d_out, int out_size, void* d_ws, size_t ws_size,
                              hipStream_t stream) {
  const float* preds = (const float*)d_in[0];
  const float* soft = (const float*)d_in[1];
  double* acc = (double*)d_ws;

  hipMemsetAsync(d_ws, 0, sizeof(double), stream);  // ws is 0xAA-poisoned

  dim3 block(BXT, BYT);
  dim3 grid((W - 2 + CX - 1) / CX, NBY + 1, BATCH);  // y==NBY -> border blocks
  cosmap_mse_kernel<<<grid, block, 0, stream>>>(preds, soft, acc);
  finalize_kernel<<<1, 1, 0, stream>>>(acc, (float*)d_out);
}

// Round 8
// 371.429 us; speedup vs baseline: 2.1811x; 1.6610x over previous
//
#include <hip/hip_runtime.h>
#include <math.h>

// CriterionLSCos: MSE between 8-neighbor cosine-similarity maps of two
// [16,19,256,256] fp32 tensors.
//
// R7 post-mortem: on this toolchain __launch_bounds__(512,w) caps VGPR at
// 256/w (measured: (512,8)->32, (512,4)->64), NOT 512/w. Kernel needs
// ~70-85 VGPR -> both caps spilled (~700MB scratch traffic, 513-703us).
// R8 = drop the occupancy demand: __launch_bounds__(NT) only, allocator
// free to use what it needs (R2's unbounded build: 44 VGPR, zero spill).
//
// Algorithm (from R2, passed):
//  - undirected-pair algebra: each forward pair (E,S,SE,SW) computed once,
//    weight 2 (1 if partner is border). Halves dot FMAs, 9-row tile.
//  - leftover backward border pairs (1522/batch) in 32 concurrent border
//    blocks (blockIdx.y==NBY).
//  - 2-deep register prefetch across the single per-channel barrier.

constexpr int BATCH = 16, CH = 19, H = 256, W = 256;
constexpr int BXT = 64, BYT = 8, NT = BXT * BYT;  // 512 threads
constexpr int CX = 128, CY = 8;                   // centers per main block
constexpr int TW2 = 66;                           // float2 slots per tile row
constexpr int TH = 9;                             // tile rows y0..y0+8
constexpr int NP = TW2 * TH;                      // 594 slots
constexpr int NBY = 32;                           // main y-blocks; by==NBY -> border
constexpr int NBORDER = 1522;                     // backward border pairs per batch

__global__ __launch_bounds__(NT)   // NO min-waves arg: let allocator avoid spill
void cosmap_mse_kernel(const float* __restrict__ preds,
                       const float* __restrict__ soft,
                       double* __restrict__ acc_out) {
  __shared__ float2 sp[2][NP];
  __shared__ float2 ss[2][NP];
  __shared__ float wsum[NT / 64];

  const int tx = threadIdx.x, ty = threadIdx.y;
  const int tid = ty * BXT + tx;
  const size_t base = (size_t)blockIdx.z * CH * H * W;

  float local = 0.f;

  if (blockIdx.y == NBY) {
    // ---------- border blocks: backward pairs whose partner is non-interior
    const float* P = preds + base;
    const float* S = soft + base;
    for (int t = blockIdx.x * NT + tid; t < NBORDER; t += 2 * NT) {
      int cy, cx, ny, nx;
      if (t < 762) {            // centers (1,x): N / NW / NE vs row 0
        int d = t / 254, k = t - d * 254;
        cy = 1; cx = 1 + k; ny = 0;
        nx = cx + (d == 0 ? 0 : (d == 1 ? -1 : 1));
      } else if (t < 1016) {    // centers (y,1): W vs col 0
        int k = t - 762; cy = 1 + k; cx = 1; ny = cy; nx = 0;
      } else if (t < 1269) {    // centers (y,1), y>=2: NW vs col 0
        int k = t - 1016; cy = 2 + k; cx = 1; ny = cy - 1; nx = 0;
      } else {                  // centers (y,254), y>=2: NE vs col 255
        int k = t - 1269; cy = 2 + k; cx = 254; ny = cy - 1; nx = 255;
      }
      const int ec = cy * W + cx, en = ny * W + nx;
      float dp = 0.f, n1 = 0.f, n2 = 0.f, dq = 0.f, m1 = 0.f, m2 = 0.f;
      for (int c = 0; c < CH; ++c) {
        const int o = c * (H * W);
        float pc = P[o + ec], pn = P[o + en];
        float sc = S[o + ec], sn = S[o + en];
        dp = fmaf(pc, pn, dp); n1 = fmaf(pc, pc, n1); n2 = fmaf(pn, pn, n2);
        dq = fmaf(sc, sn, dq); m1 = fmaf(sc, sc, m1); m2 = fmaf(sn, sn, m2);
      }
      float mp = dp * (1.0f / sqrtf(n1)) * (1.0f / sqrtf(n2));
      float ms = dq * (1.0f / sqrtf(m1)) * (1.0f / sqrtf(m2));
      float d = mp - ms;
      local = fmaf(d, d, local);  // weight 1
    }
  } else {
    // ---------- main blocks: forward pairs E,S,SE,SW
    const int x0 = 1 + blockIdx.x * CX;
    const int y0 = 1 + blockIdx.y * CY;

    const int p0 = tid;
    const bool has2 = tid < (NP - NT);  // 82 threads own a second slot
    const int p1 = has2 ? tid + NT : tid;

    bool ov0, ov1; int f0, f1;
    {
      int j = p0 / TW2, i2 = p0 - j * TW2;
      int gy = y0 + j; gy = gy > H - 1 ? H - 1 : gy;
      int gs = x0 - 1 + 2 * i2;
      ov0 = gs >= W - 1;
      f0 = (gy * W + (ov0 ? W - 2 : gs)) >> 1;
    }
    {
      int j = p1 / TW2, i2 = p1 - j * TW2;
      int gy = y0 + j; gy = gy > H - 1 ? H - 1 : gy;
      int gs = x0 - 1 + 2 * i2;
      ov1 = gs >= W - 1;
      f1 = (gy * W + (ov1 ? W - 2 : gs)) >> 1;
    }

    const float2* pp = (const float2*)(preds + base);
    const float2* qq = (const float2*)(soft + base);
    constexpr int CS2 = H * W / 2;

    // 2-deep prefetch: A = ch, B = ch+1 in flight
    float2 Ap0 = pp[f0], Aq0 = qq[f0], Ap1 = pp[f1], Aq1 = qq[f1];
    float2 Bp0 = pp[f0 + CS2], Bq0 = qq[f0 + CS2];
    float2 Bp1 = pp[f1 + CS2], Bq1 = qq[f1 + CS2];

    float dE0 = 0, dS0 = 0, dSE0 = 0, dSW0 = 0;
    float dE1 = 0, dS1 = 0, dSE1 = 0, dSW1 = 0;
    float eE0 = 0, eS0 = 0, eSE0 = 0, eSW0 = 0;
    float eE1 = 0, eS1 = 0, eSE1 = 0, eSW1 = 0;
    float2 np0 = {0, 0}, np1 = {0, 0}, nq0 = {0, 0}, nq1 = {0, 0};

    const int r0 = ty * TW2 + tx;

#pragma unroll 2
    for (int ch = 0; ch < CH; ++ch) {
      float2* SP = sp[ch & 1];
      float2* SS = ss[ch & 1];
      float2 wp0 = Ap0; if (ov0) wp0.x = wp0.y;
      float2 wq0 = Aq0; if (ov0) wq0.x = wq0.y;
      float2 wp1 = Ap1; if (ov1) wp1.x = wp1.y;
      float2 wq1 = Aq1; if (ov1) wq1.x = wq1.y;
      SP[p0] = wp0; SS[p0] = wq0;
      if (has2) { SP[p1] = wp1; SS[p1] = wq1; }
      np0.x = fmaf(wp0.x, wp0.x, np0.x); np0.y = fmaf(wp0.y, wp0.y, np0.y);
      nq0.x = fmaf(wq0.x, wq0.x, nq0.x); nq0.y = fmaf(wq0.y, wq0.y, nq0.y);
      if (has2) {
        np1.x = fmaf(wp1.x, wp1.x, np1.x); np1.y = fmaf(wp1.y, wp1.y, np1.y);
        nq1.x = fmaf(wq1.x, wq1.x, nq1.x); nq1.y = fmaf(wq1.y, wq1.y, nq1.y);
      }
      Ap0 = Bp0; Aq0 = Bq0; Ap1 = Bp1; Aq1 = Bq1;
      if (ch + 2 < CH) {
        const int o = (ch + 2) * CS2;
        Bp0 = pp[f0 + o]; Bq0 = qq[f0 + o];
        Bp1 = pp[f1 + o]; Bq1 = qq[f1 + o];
      }
      __syncthreads();
      {
        float2 m0 = SP[r0], m1 = SP[r0 + 1];
        float2 l0 = SP[r0 + TW2], l1 = SP[r0 + TW2 + 1];
        dE0  = fmaf(m0.y, m1.x, dE0);   dE1  = fmaf(m1.x, m1.y, dE1);
        dS0  = fmaf(m0.y, l0.y, dS0);   dS1  = fmaf(m1.x, l1.x, dS1);
        dSE0 = fmaf(m0.y, l1.x, dSE0);  dSE1 = fmaf(m1.x, l1.y, dSE1);
        dSW0 = fmaf(m0.y, l0.x, dSW0);  dSW1 = fmaf(m1.x, l0.y, dSW1);
      }
      {
        float2 m0 = SS[r0], m1 = SS[r0 + 1];
        float2 l0 = SS[r0 + TW2], l1 = SS[r0 + TW2 + 1];
        eE0  = fmaf(m0.y, m1.x, eE0);   eE1  = fmaf(m1.x, m1.y, eE1);
        eS0  = fmaf(m0.y, l0.y, eS0);   eS1  = fmaf(m1.x, l1.x, eS1);
        eSE0 = fmaf(m0.y, l1.x, eSE0);  eSE1 = fmaf(m1.x, l1.y, eSE1);
        eSW0 = fmaf(m0.y, l0.x, eSW0);  eSW1 = fmaf(m1.x, l0.y, eSW1);
      }
    }

    // inverse norms -> buffer 1
    {
      float2 r;
      r.x = 1.0f / sqrtf(np0.x); r.y = 1.0f / sqrtf(np0.y); sp[1][p0] = r;
      r.x = 1.0f / sqrtf(nq0.x); r.y = 1.0f / sqrtf(nq0.y); ss[1][p0] = r;
      if (has2) {
        r.x = 1.0f / sqrtf(np1.x); r.y = 1.0f / sqrtf(np1.y); sp[1][p1] = r;
        r.x = 1.0f / sqrtf(nq1.x); r.y = 1.0f / sqrtf(nq1.y); ss[1][p1] = r;
      }
    }
    __syncthreads();

    {
      const float2* RP = sp[1];
      const float2* RS = ss[1];
      float2 rm0 = RP[r0], rm1 = RP[r0 + 1];
      float2 rl0 = RP[r0 + TW2], rl1 = RP[r0 + TW2 + 1];
      float2 tm0 = RS[r0], tm1 = RS[r0 + 1];
      float2 tl0 = RS[r0 + TW2], tl1 = RS[r0 + TW2 + 1];

      const int px0 = x0 + 2 * tx, px1 = px0 + 1, py = y0 + ty;
      const bool vy = py <= H - 2;
      const float wS = (py + 1 <= H - 2) ? 2.f : 1.f;

      if (vy && px0 <= W - 2) {
        const float wE  = (px0 + 1 <= W - 2) ? 2.f : 1.f;
        const float wSE = (px0 + 1 <= W - 2) ? wS : 1.f;
        const float wSW = (px0 - 1 >= 1) ? wS : 1.f;
        float d;
        d = dE0  * rm0.y * rm1.x - eE0  * tm0.y * tm1.x; local = fmaf(wE  * d, d, local);
        d = dS0  * rm0.y * rl0.y - eS0  * tm0.y * tl0.y; local = fmaf(wS  * d, d, local);
        d = dSE0 * rm0.y * rl1.x - eSE0 * tm0.y * tl1.x; local = fmaf(wSE * d, d, local);
        d = dSW0 * rm0.y * rl0.x - eSW0 * tm0.y * tl0.x; local = fmaf(wSW * d, d, local);
      }
      if (vy && px1 <= W - 2) {
        const float wE  = (px1 + 1 <= W - 2) ? 2.f : 1.f;
        const float wSE = (px1 + 1 <= W - 2) ? wS : 1.f;
        const float wSW = (px1 - 1 >= 1) ? wS : 1.f;
        float d;
        d = dE1  * rm1.x * rm1.y - eE1  * tm1.x * tm1.y; local = fmaf(wE  * d, d, local);
        d = dS1  * rm1.x * rl1.x - eS1  * tm1.x * tl1.x; local = fmaf(wS  * d, d, local);
        d = dSE1 * rm1.x * rl1.y - eSE1 * tm1.x * tl1.y; local = fmaf(wSE * d, d, local);
        d = dSW1 * rm1.x * rl0.y - eSW1 * tm1.x * tl0.y; local = fmaf(wSW * d, d, local);
      }
    }
  }

  // ---------- block reduction (both paths)
#pragma unroll
  for (int o = 32; o > 0; o >>= 1) local += __shfl_down(local, o, 64);
  if ((tid & 63) == 0) wsum[tid >> 6] = local;
  __syncthreads();
  if (tid == 0) {
    float s = 0.f;
#pragma unroll
    for (int w = 0; w < NT / 64; ++w) s += wsum[w];
    atomicAdd(acc_out, (double)s);
  }
}

__global__ void finalize_kernel(const double* __restrict__ acc,
                                float* __restrict__ out) {
  constexpr double cnt = (double)BATCH * 8.0 * (H - 2) * (W - 2);
  out[0] = (float)(acc[0] / cnt);
}

extern "C" void kernel_launch(void* const* d_in, const int* in_sizes, int n_in,
                              void* d_out, int out_size, void* d_ws, size_t ws_size,
                              hipStream_t stream) {
  const float* preds = (const float*)d_in[0];
  const float* soft = (const float*)d_in[1];
  double* acc = (double*)d_ws;

  hipMemsetAsync(d_ws, 0, sizeof(double), stream);  // ws is 0xAA-poisoned

  dim3 block(BXT, BYT);
  dim3 grid((W - 2 + CX - 1) / CX, NBY + 1, BATCH);  // y==NBY -> border blocks
  cosmap_mse_kernel<<<grid, block, 0, stream>>>(preds, soft, acc);
  finalize_kernel<<<1, 1, 0, stream>>>(acc, (float*)d_out);
}

// Round 10
// 210.153 us; speedup vs baseline: 3.8549x; 1.7674x over previous
//
#include <hip/hip_runtime.h>
#include <math.h>

// CriterionLSCos: MSE between 8-neighbor cosine-similarity maps of two
// [16,19,256,256] fp32 tensors.
//
// R9 redesign (unchanged resubmit — R9 bench was a broker timeout).
// R3-R8 evidence: the tiled-LDS structure spilled at every launch-bounds
// setting (demands >128 VGPR) and carried a fixed 785920 LDS bank-conflict
// count. This version removes the failure modes structurally:
//   - NO LDS, NO __syncthreads: one wave == one full image row
//     (64 lanes x 4 px = W). All x-neighbor values AND norms travel by
//     intra-wave __shfl. Vertical (row) reuse is served by L1/L2.
//   - per channel per wave: 6 aligned float4 loads (rows y-1,y,y+1 x two
//     tensors, 16B/lane), 12 shuffles, ~100 FMA. 1-deep prefetch.
//   - norms computed once per pixel (3 rows x 4 px per thread); neighbor
//     norms at epilogue via shfl of the precomputed rsqrt values.
//   - per-wave shuffle reduction -> one double atomicAdd per wave.
// All arrays are constant-indexed after full unroll (no scratch).

constexpr int BATCH = 16, CH = 19, H = 256, W = 256;
constexpr int HW = H * W;
constexpr int CS4 = HW / 4;  // channel stride in float4

__global__ __launch_bounds__(256)   // no min-waves arg (R7/R8 lesson)
void cosmap_mse_kernel(const float* __restrict__ preds,
                       const float* __restrict__ soft,
                       double* __restrict__ acc_out) {
  const int lane = threadIdx.x & 63;
  const int wid = threadIdx.x >> 6;
  const int y = 1 + (blockIdx.y << 2) + wid;   // this wave's center row
  if (y > H - 2) return;                       // wave-uniform, no barriers below
  const size_t base = (size_t)blockIdx.z * (CH * HW);

  // row pointers (float4 granularity), lane offset folded in
  const float4* PU = (const float4*)(preds + base + (size_t)(y - 1) * W) + lane;
  const float4* PM = PU + (W / 4);
  const float4* PL = PM + (W / 4);
  const float4* SU = (const float4*)(soft + base + (size_t)(y - 1) * W) + lane;
  const float4* SM = SU + (W / 4);
  const float4* SL = SM + (W / 4);

  float dp[8][4], dq[8][4];   // 8 directions x 4 centers, preds/soft
  float np[3][4], nq[3][4];   // self-norms rows {u,m,l} x 4 px
#pragma unroll
  for (int d = 0; d < 8; ++d)
#pragma unroll
    for (int e = 0; e < 4; ++e) { dp[d][e] = 0.f; dq[d][e] = 0.f; }
#pragma unroll
  for (int r = 0; r < 3; ++r)
#pragma unroll
    for (int e = 0; e < 4; ++e) { np[r][e] = 0.f; nq[r][e] = 0.f; }

  // 1-deep prefetch (no barriers -> loads overlap previous channel's FMAs)
  float4 au = PU[0], am = PM[0], al = PL[0];
  float4 bu = SU[0], bm = SM[0], bl = SL[0];

  for (int c = 0; c < CH; ++c) {
    const float4 cu = au, cm = am, cl = al, eu = bu, em = bm, el = bl;
    if (c + 1 < CH) {
      const int o = (c + 1) * CS4;
      au = PU[o]; am = PM[o]; al = PL[o];
      bu = SU[o]; bm = SM[o]; bl = SL[o];
    }
    // x-window [4*lane-1 .. 4*lane+4]; wrap lanes feed only masked centers
    const float wu[6] = {__shfl_up(cu.w, 1), cu.x, cu.y, cu.z, cu.w, __shfl_down(cu.x, 1)};
    const float wm[6] = {__shfl_up(cm.w, 1), cm.x, cm.y, cm.z, cm.w, __shfl_down(cm.x, 1)};
    const float wl[6] = {__shfl_up(cl.w, 1), cl.x, cl.y, cl.z, cl.w, __shfl_down(cl.x, 1)};
    const float vu[6] = {__shfl_up(eu.w, 1), eu.x, eu.y, eu.z, eu.w, __shfl_down(eu.x, 1)};
    const float vm[6] = {__shfl_up(em.w, 1), em.x, em.y, em.z, em.w, __shfl_down(em.x, 1)};
    const float vl[6] = {__shfl_up(el.w, 1), el.x, el.y, el.z, el.w, __shfl_down(el.x, 1)};
#pragma unroll
    for (int e = 0; e < 4; ++e) {
      np[0][e] = fmaf(wu[e + 1], wu[e + 1], np[0][e]);
      np[1][e] = fmaf(wm[e + 1], wm[e + 1], np[1][e]);
      np[2][e] = fmaf(wl[e + 1], wl[e + 1], np[2][e]);
      nq[0][e] = fmaf(vu[e + 1], vu[e + 1], nq[0][e]);
      nq[1][e] = fmaf(vm[e + 1], vm[e + 1], nq[1][e]);
      nq[2][e] = fmaf(vl[e + 1], vl[e + 1], nq[2][e]);
      const float cp = wm[e + 1], cs = vm[e + 1];
      dp[0][e] = fmaf(cp, wu[e],     dp[0][e]); dq[0][e] = fmaf(cs, vu[e],     dq[0][e]); // NW
      dp[1][e] = fmaf(cp, wu[e + 1], dp[1][e]); dq[1][e] = fmaf(cs, vu[e + 1], dq[1][e]); // N
      dp[2][e] = fmaf(cp, wu[e + 2], dp[2][e]); dq[2][e] = fmaf(cs, vu[e + 2], dq[2][e]); // NE
      dp[3][e] = fmaf(cp, wm[e],     dp[3][e]); dq[3][e] = fmaf(cs, vm[e],     dq[3][e]); // W
      dp[4][e] = fmaf(cp, wm[e + 2], dp[4][e]); dq[4][e] = fmaf(cs, vm[e + 2], dq[4][e]); // E
      dp[5][e] = fmaf(cp, wl[e],     dp[5][e]); dq[5][e] = fmaf(cs, vl[e],     dq[5][e]); // SW
      dp[6][e] = fmaf(cp, wl[e + 1], dp[6][e]); dq[6][e] = fmaf(cs, vl[e + 1], dq[6][e]); // S
      dp[7][e] = fmaf(cp, wl[e + 2], dp[7][e]); dq[7][e] = fmaf(cs, vl[e + 2], dq[7][e]); // SE
    }
  }

  // inverse norms (one per pixel), then neighbor-norm windows via shfl
  float rp[3][4], rq[3][4];
#pragma unroll
  for (int r = 0; r < 3; ++r)
#pragma unroll
    for (int e = 0; e < 4; ++e) {
      rp[r][e] = 1.0f / sqrtf(np[r][e]);
      rq[r][e] = 1.0f / sqrtf(nq[r][e]);
    }

  const float xu[6] = {__shfl_up(rp[0][3], 1), rp[0][0], rp[0][1], rp[0][2], rp[0][3], __shfl_down(rp[0][0], 1)};
  const float xm[6] = {__shfl_up(rp[1][3], 1), rp[1][0], rp[1][1], rp[1][2], rp[1][3], __shfl_down(rp[1][0], 1)};
  const float xl[6] = {__shfl_up(rp[2][3], 1), rp[2][0], rp[2][1], rp[2][2], rp[2][3], __shfl_down(rp[2][0], 1)};
  const float zu[6] = {__shfl_up(rq[0][3], 1), rq[0][0], rq[0][1], rq[0][2], rq[0][3], __shfl_down(rq[0][0], 1)};
  const float zm[6] = {__shfl_up(rq[1][3], 1), rq[1][0], rq[1][1], rq[1][2], rq[1][3], __shfl_down(rq[1][0], 1)};
  const float zl[6] = {__shfl_up(rq[2][3], 1), rq[2][0], rq[2][1], rq[2][2], rq[2][3], __shfl_down(rq[2][0], 1)};

  float local = 0.f;
#pragma unroll
  for (int e = 0; e < 4; ++e) {
    const int x = (lane << 2) + e;
    if (x >= 1 && x <= W - 2) {
      const float rcp = rp[1][e], rcq = rq[1][e];
      float mp, ms, t;
      mp = dp[0][e] * rcp * xu[e];     ms = dq[0][e] * rcq * zu[e];     t = mp - ms; local = fmaf(t, t, local);
      mp = dp[1][e] * rcp * xu[e + 1]; ms = dq[1][e] * rcq * zu[e + 1]; t = mp - ms; local = fmaf(t, t, local);
      mp = dp[2][e] * rcp * xu[e + 2]; ms = dq[2][e] * rcq * zu[e + 2]; t = mp - ms; local = fmaf(t, t, local);
      mp = dp[3][e] * rcp * xm[e];     ms = dq[3][e] * rcq * zm[e];     t = mp - ms; local = fmaf(t, t, local);
      mp = dp[4][e] * rcp * xm[e + 2]; ms = dq[4][e] * rcq * zm[e + 2]; t = mp - ms; local = fmaf(t, t, local);
      mp = dp[5][e] * rcp * xl[e];     ms = dq[5][e] * rcq * zl[e];     t = mp - ms; local = fmaf(t, t, local);
      mp = dp[6][e] * rcp * xl[e + 1]; ms = dq[6][e] * rcq * zl[e + 1]; t = mp - ms; local = fmaf(t, t, local);
      mp = dp[7][e] * rcp * xl[e + 2]; ms = dq[7][e] * rcq * zl[e + 2]; t = mp - ms; local = fmaf(t, t, local);
    }
  }

  // per-wave reduction, one atomic per wave (no LDS, no barrier)
#pragma unroll
  for (int o = 32; o > 0; o >>= 1) local += __shfl_down(local, o, 64);
  if (lane == 0) atomicAdd(acc_out, (double)local);
}

__global__ void finalize_kernel(const double* __restrict__ acc,
                                float* __restrict__ out) {
  constexpr double cnt = (double)BATCH * 8.0 * (H - 2) * (W - 2);
  out[0] = (float)(acc[0] / cnt);
}

extern "C" void kernel_launch(void* const* d_in, const int* in_sizes, int n_in,
                              void* d_out, int out_size, void* d_ws, size_t ws_size,
                              hipStream_t stream) {
  const float* preds = (const float*)d_in[0];
  const float* soft = (const float*)d_in[1];
  double* acc = (double*)d_ws;

  hipMemsetAsync(d_ws, 0, sizeof(double), stream);  // ws is 0xAA-poisoned

  // 4 rows per block (4 waves), rows 1..254 -> grid.y = 64
  dim3 block(256);
  dim3 grid(1, (H - 2 + 3) / 4, BATCH);
  cosmap_mse_kernel<<<grid, block, 0, stream>>>(preds, soft, acc);
  finalize_kernel<<<1, 1, 0, stream>>>(acc, (float*)d_out);
}